// Round 4
// baseline (393.051 us; speedup 1.0000x reference)
//
#include <hip/hip_runtime.h>
#include <math.h>

#define KC 24
constexpr int D = 16;
constexpr int B = 4;
constexpr int N = 512 * 1024;          // points per image, 2^19
constexpr float DELTA_VAR = 1.0f;
constexpr float DELTA_DIST = 2.0f;

constexpr int REP = 8;                 // LDS accumulator replicas (replica = t&7)
constexpr int RS  = KC * 17;           // 408 words per sum replica
constexpr int CS  = 33;
constexpr int TPB = 512;
constexpr int PTS = 8192;              // points per block
constexpr int NBLK = (B * N) / PTS;    // 256 blocks; 147KB LDS forces 1 block/CU -> all resident
constexpr int SL = 8;                  // global accumulator slices
constexpr int RREG = 8;                // planes retained in VGPRs across barrier (128 regs)
constexpr int RLDS = 4;                // planes retained in LDS across barrier (128 KB)
constexpr int WS_FLOATS = SL * (B * KC * D) + SL * (B * KC) + 64;  // 13120

// ws: g_sums [SL][B*KC*D] | g_cnt [SL][B*KC] | g_varp [64] | barrier {cnt,gen}

__device__ __forceinline__ float gldf(const float* p) {
    return __hip_atomic_load(p, __ATOMIC_RELAXED, __HIP_MEMORY_SCOPE_AGENT);
}

// sense-reversing grid barrier; bounded spin so a residency failure fails visibly, not hangs
__device__ __forceinline__ void gsync(int* cnt, int* gen) {
    __syncthreads();
    if (threadIdx.x == 0) {
        int g = __hip_atomic_load(gen, __ATOMIC_ACQUIRE, __HIP_MEMORY_SCOPE_AGENT);
        if (__hip_atomic_fetch_add(cnt, 1, __ATOMIC_ACQ_REL, __HIP_MEMORY_SCOPE_AGENT) == NBLK - 1) {
            __hip_atomic_store(cnt, 0, __ATOMIC_RELAXED, __HIP_MEMORY_SCOPE_AGENT);
            __hip_atomic_fetch_add(gen, 1, __ATOMIC_ACQ_REL, __HIP_MEMORY_SCOPE_AGENT);
        } else {
            for (int it = 0; it < (1 << 22); ++it) {
                if (__hip_atomic_load(gen, __ATOMIC_ACQUIRE, __HIP_MEMORY_SCOPE_AGENT) != g) break;
                __builtin_amdgcn_s_sleep(8);
            }
        }
    }
    __syncthreads();
}

__global__ __launch_bounds__(TPB, 2) void k_fused(const float* __restrict__ data,
                                                  const int* __restrict__ labels,
                                                  float* __restrict__ ws,
                                                  float* __restrict__ out) {
    __shared__ float s_sum[REP * RS];                    // 13056 B
    __shared__ float s_cnt[REP * CS];                    // 1056 B
    __shared__ __align__(16) float4 s_data4[RLDS][PTS / 4];  // 131072 B
    __shared__ float s_c[KC * 17];                       // 1632 B
    __shared__ float s_ic[KC];
    __shared__ float s_red[8];

    float* g_sums = ws;
    float* g_cnt  = ws + SL * (B * KC * D);
    float* g_varp = g_cnt + SL * (B * KC);
    int*   bar    = (int*)(g_varp + 64);

    const int t = threadIdx.x;
    const int chunk = blockIdx.x * PTS;
    const int b = chunk >> 19;
    const float* base = data + (size_t)(b * D) * N + (chunk & (N - 1));

    // early global loads (labels + plane 0) overlap the LDS zeroing
    int4 lab[4];
#pragma unroll
    for (int i = 0; i < 4; ++i)
        lab[i] = *(const int4*)(labels + chunk + (i * TPB + t) * 4);

    float4 vr[RREG][4];
#pragma unroll
    for (int i = 0; i < 4; ++i)
        vr[0][i] = *(const float4*)(base + (i * TPB + t) * 4);

    for (int i = t; i < REP * RS; i += TPB) s_sum[i] = 0.f;
    for (int i = t; i < REP * CS; i += TPB) s_cnt[i] = 0.f;
    __syncthreads();

    const int rbase = (t & 7) * RS;
    const int cbase = (t & 7) * CS;
#pragma unroll
    for (int i = 0; i < 4; ++i) {
        atomicAdd(&s_cnt[cbase + lab[i].x], 1.f);
        atomicAdd(&s_cnt[cbase + lab[i].y], 1.f);
        atomicAdd(&s_cnt[cbase + lab[i].z], 1.f);
        atomicAdd(&s_cnt[cbase + lab[i].w], 1.f);
    }

    // ---- phase 1: d-sequential accumulate; retain planes 0..RREG+RLDS-1 ----
    float4 v[2][4];
#pragma unroll
    for (int d = 0; d < D; ++d) {
        if (d + 1 < D) {
#pragma unroll
            for (int i = 0; i < 4; ++i) {
                float4 nx = *(const float4*)(base + (size_t)(d + 1) * N + (i * TPB + t) * 4);
                if (d + 1 < RREG) vr[d + 1][i] = nx;
                else              v[(d + 1) & 1][i] = nx;
            }
        }
#pragma unroll
        for (int i = 0; i < 4; ++i) {
            const float4 c = (d < RREG) ? vr[d][i] : v[d & 1][i];
            if (d >= RREG && d < RREG + RLDS) s_data4[d - RREG][i * TPB + t] = c;
            atomicAdd(&s_sum[rbase + lab[i].x * 17 + d], c.x);
            atomicAdd(&s_sum[rbase + lab[i].y * 17 + d], c.y);
            atomicAdd(&s_sum[rbase + lab[i].z * 17 + d], c.z);
            atomicAdd(&s_sum[rbase + lab[i].w * 17 + d], c.w);
        }
    }
    __syncthreads();

    // epilogue: rotated order + per-slice targets
    const int slice = blockIdx.x & (SL - 1);
    float* gs = g_sums + slice * (B * KC * D) + b * (KC * D);
    float* gc = g_cnt  + slice * (B * KC)     + b * KC;
    const int rot = (blockIdx.x * 131) & 255;
    for (int i = t; i < KC * D; i += TPB) {
        int j = (i + rot) % (KC * D);
        int c = j >> 4, dd = j & 15;
        float s = 0.f;
#pragma unroll
        for (int r = 0; r < REP; ++r) s += s_sum[r * RS + c * 17 + dd];
        atomicAdd(&gs[j], s);
    }
    if (t < KC) {
        float s = 0.f;
#pragma unroll
        for (int r = 0; r < REP; ++r) s += s_cnt[r * CS + t];
        atomicAdd(&gc[t], s);
    }

    // prefetch first tail plane (input is read-only: safe before the barrier)
#pragma unroll
    for (int i = 0; i < 4; ++i)
        v[0][i] = *(const float4*)(base + (size_t)(RREG + RLDS) * N + (i * TPB + t) * 4);

    gsync(bar, bar + 1);   // sums + counts final

    // ---- phase 2: centers + hinged variance ----
    if (t < KC) {
        float cn = 0.f;
#pragma unroll
        for (int r = 0; r < SL; ++r) cn += gldf(&g_cnt[r * (B * KC) + b * KC + t]);
        s_ic[t] = 1.f / cn;
    }
    __syncthreads();
    for (int i = t; i < KC * D; i += TPB) {
        int c = i >> 4, dd = i & 15;
        float s = 0.f;
#pragma unroll
        for (int r = 0; r < SL; ++r) s += gldf(&g_sums[r * (B * KC * D) + b * (KC * D) + i]);
        s_c[c * 17 + dd] = s * s_ic[c];
    }
    __syncthreads();

    float ac[16];
#pragma unroll
    for (int i = 0; i < 16; ++i) ac[i] = 0.f;

#pragma unroll
    for (int d = 0; d < RREG; ++d) {
#pragma unroll
        for (int i = 0; i < 4; ++i) {
            const float4 c = vr[d][i];
            float df;
            df = c.x - s_c[lab[i].x * 17 + d]; ac[i * 4 + 0] += df * df;
            df = c.y - s_c[lab[i].y * 17 + d]; ac[i * 4 + 1] += df * df;
            df = c.z - s_c[lab[i].z * 17 + d]; ac[i * 4 + 2] += df * df;
            df = c.w - s_c[lab[i].w * 17 + d]; ac[i * 4 + 3] += df * df;
        }
    }
#pragma unroll
    for (int p = 0; p < RLDS; ++p) {
        const int d = RREG + p;
#pragma unroll
        for (int i = 0; i < 4; ++i) {
            const float4 c = s_data4[p][i * TPB + t];
            float df;
            df = c.x - s_c[lab[i].x * 17 + d]; ac[i * 4 + 0] += df * df;
            df = c.y - s_c[lab[i].y * 17 + d]; ac[i * 4 + 1] += df * df;
            df = c.z - s_c[lab[i].z * 17 + d]; ac[i * 4 + 2] += df * df;
            df = c.w - s_c[lab[i].w * 17 + d]; ac[i * 4 + 3] += df * df;
        }
    }
#pragma unroll
    for (int dd = 0; dd < D - RREG - RLDS; ++dd) {
        const int d = RREG + RLDS + dd;
        if (dd + 1 < D - RREG - RLDS) {
#pragma unroll
            for (int i = 0; i < 4; ++i)
                v[(dd + 1) & 1][i] =
                    *(const float4*)(base + (size_t)(d + 1) * N + (i * TPB + t) * 4);
        }
#pragma unroll
        for (int i = 0; i < 4; ++i) {
            const float4 c = v[dd & 1][i];
            float df;
            df = c.x - s_c[lab[i].x * 17 + d]; ac[i * 4 + 0] += df * df;
            df = c.y - s_c[lab[i].y * 17 + d]; ac[i * 4 + 1] += df * df;
            df = c.z - s_c[lab[i].z * 17 + d]; ac[i * 4 + 2] += df * df;
            df = c.w - s_c[lab[i].w * 17 + d]; ac[i * 4 + 3] += df * df;
        }
    }

    float hsum = 0.f;
#pragma unroll
    for (int i = 0; i < 4; ++i) {
        float h;
        h = fmaxf(sqrtf(ac[i * 4 + 0]) - DELTA_VAR, 0.f); hsum += h * h * s_ic[lab[i].x];
        h = fmaxf(sqrtf(ac[i * 4 + 1]) - DELTA_VAR, 0.f); hsum += h * h * s_ic[lab[i].y];
        h = fmaxf(sqrtf(ac[i * 4 + 2]) - DELTA_VAR, 0.f); hsum += h * h * s_ic[lab[i].z];
        h = fmaxf(sqrtf(ac[i * 4 + 3]) - DELTA_VAR, 0.f); hsum += h * h * s_ic[lab[i].w];
    }
    for (int o = 32; o > 0; o >>= 1) hsum += __shfl_down(hsum, o, 64);
    if ((t & 63) == 0) s_red[t >> 6] = hsum;
    __syncthreads();
    if (t == 0) {
        float s = 0.f;
#pragma unroll
        for (int w = 0; w < 8; ++w) s += s_red[w];
        atomicAdd(&g_varp[blockIdx.x & 63], s);
    }

    gsync(bar, bar + 1);   // varp final

    if (blockIdx.x != 0) return;

    // ---- finalize (block 0): var + dist + reg -> scalar ----
    float* s_cF = (float*)&s_data4[0][0];   // reuse 128 KB region; needs 6528 floats
    float acc = 0.f;
    if (t < B * KC) {
        float cnt = 0.f;
#pragma unroll
        for (int r = 0; r < SL; ++r) cnt += gldf(&g_cnt[r * (B * KC) + t]);
        float ns = 0.f;
        for (int dd = 0; dd < D; ++dd) {
            float s = 0.f;
#pragma unroll
            for (int r = 0; r < SL; ++r) s += gldf(&g_sums[r * (B * KC * D) + t * D + dd]);
            float c = s / cnt;
            s_cF[t * 17 + dd] = c;
            ns += c * c;
        }
        acc = sqrtf(ns) / (float)KC;
    }
    if (t < 64) acc += gldf(&g_varp[t]);
    __syncthreads();

    float dacc = 0.f;  // raw sum over [B,K,K] incl. diagonal (= delta_dist^2 each)
    for (int idx = t; idx < B * KC * KC; idx += TPB) {
        int bb = idx / (KC * KC);
        int r = idx % (KC * KC);
        int i = r / KC, j = r % KC;
        float hd;
        if (i == j) {
            hd = DELTA_DIST * DELTA_DIST;
        } else {
            const float* ci = &s_cF[(bb * KC + i) * 17];
            const float* cj = &s_cF[(bb * KC + j) * 17];
            float sq = 0.f;
            for (int dd = 0; dd < D; ++dd) { float df = ci[dd] - cj[dd]; sq += df * df; }
            float hh = fmaxf(DELTA_DIST - sqrtf(sq), 0.f);
            hd = hh * hh;
        }
        dacc += hd;
    }
    float total = acc + dacc / (2.f * KC * (KC - 1));

    for (int o = 32; o > 0; o >>= 1) total += __shfl_down(total, o, 64);
    if ((t & 63) == 0) s_red[t >> 6] = total;
    __syncthreads();
    if (t == 0) {
        float s = 0.f;
#pragma unroll
        for (int w = 0; w < 8; ++w) s += s_red[w];
        out[0] = s / (float)B;
    }
}

extern "C" void kernel_launch(void* const* d_in, const int* in_sizes, int n_in,
                              void* d_out, int out_size, void* d_ws, size_t ws_size,
                              hipStream_t stream) {
    const float* data  = (const float*)d_in[0];
    const int* labels  = (const int*)d_in[1];
    float* ws          = (float*)d_ws;

    hipMemsetAsync(d_ws, 0, WS_FLOATS * sizeof(float) + 2 * sizeof(int), stream);
    k_fused<<<NBLK, TPB, 0, stream>>>(data, labels, ws, (float*)d_out);
}